// Round 1
// baseline (20369.510 us; speedup 1.0000x reference)
//
#include <hip/hip_runtime.h>
#include <hip/hip_bf16.h>

// Problem constants
#define HSZ 1024
#define VSZ 32000
#define BSZ 16
#define SSZ 256
#define TSZ 200

__device__ __forceinline__ float wsum(float v) {
    #pragma unroll
    for (int o = 32; o; o >>= 1) v += __shfl_xor(v, o, 64);
    return v;
}
__device__ __forceinline__ float fast_tanh(float x) {
    x = fminf(15.f, fmaxf(-15.f, x));
    float e = __expf(2.f * x);
    return (e - 1.f) / (e + 1.f);
}
__device__ __forceinline__ float sigmoidf(float x) {
    return 1.f / (1.f + __expf(-x));
}

// tok[m = t*B + b] = (t==0) ? SOS : target[b][t-1]
__global__ __launch_bounds__(256) void build_tokens(const int* __restrict__ targ,
                                                    int* __restrict__ tok) {
    int m = blockIdx.x * 256 + threadIdx.x;
    if (m >= TSZ * BSZ) return;
    int t = m >> 4, b = m & 15;
    tok[m] = (t == 0) ? 1 : targ[b * TSZ + (t - 1)];
}

// C[m][n] = sum_k A[row(m)][k] * B[n][k] + bias[n] + bias2[n]
// A: lda == K (row-major), optional gather of A rows. B: row stride ldb.
__global__ __launch_bounds__(256) void gemm_nt(
    const float* __restrict__ A, const int* __restrict__ gather,
    const float* __restrict__ B, int ldb,
    const float* __restrict__ bias, const float* __restrict__ bias2,
    float* __restrict__ C, int M, int N, int K)
{
    __shared__ float As[16][64];
    __shared__ float Bs[16][64];
    int m0 = blockIdx.y * 64, n0 = blockIdx.x * 64;
    int t = threadIdx.x;
    int lr = t >> 2;            // 0..63
    int lk = (t & 3) * 4;       // 0,4,8,12
    int arow = m0 + lr;
    const float* Ar = A + (size_t)(gather ? gather[arow] : arow) * K;
    const float* Br = B + (size_t)(n0 + lr) * ldb;
    int tm = (t & 15) * 4, tn = (t >> 4) * 4;
    float acc[4][4] = {};
    for (int k0 = 0; k0 < K; k0 += 16) {
        float4 av = *(const float4*)(Ar + k0 + lk);
        float4 bv = *(const float4*)(Br + k0 + lk);
        __syncthreads();
        As[lk + 0][lr] = av.x; As[lk + 1][lr] = av.y;
        As[lk + 2][lr] = av.z; As[lk + 3][lr] = av.w;
        Bs[lk + 0][lr] = bv.x; Bs[lk + 1][lr] = bv.y;
        Bs[lk + 2][lr] = bv.z; Bs[lk + 3][lr] = bv.w;
        __syncthreads();
        #pragma unroll
        for (int kk = 0; kk < 16; ++kk) {
            float4 a = *(const float4*)&As[kk][tm];
            float4 b = *(const float4*)&Bs[kk][tn];
            acc[0][0] += a.x * b.x; acc[0][1] += a.x * b.y; acc[0][2] += a.x * b.z; acc[0][3] += a.x * b.w;
            acc[1][0] += a.y * b.x; acc[1][1] += a.y * b.y; acc[1][2] += a.y * b.z; acc[1][3] += a.y * b.w;
            acc[2][0] += a.z * b.x; acc[2][1] += a.z * b.y; acc[2][2] += a.z * b.z; acc[2][3] += a.z * b.w;
            acc[3][0] += a.w * b.x; acc[3][1] += a.w * b.y; acc[3][2] += a.w * b.z; acc[3][3] += a.w * b.w;
        }
    }
    float bb[4];
    #pragma unroll
    for (int i = 0; i < 4; ++i)
        bb[i] = (bias ? bias[n0 + tn + i] : 0.f) + (bias2 ? bias2[n0 + tn + i] : 0.f);
    #pragma unroll
    for (int mi = 0; mi < 4; ++mi)
        #pragma unroll
        for (int ni = 0; ni < 4; ++ni)
            C[(size_t)(m0 + tm + mi) * N + n0 + tn + ni] = acc[mi][ni] + bb[ni];
}

// K1: qp = h1@Wa^T + Wa_b ; hh0 = h0@W_hh0^T (gates i,g,o) ; hh1p = h1@W_hh1^T (i,g,o)
__global__ __launch_bounds__(256) void step_pre(
    const float* __restrict__ h0p, const float* __restrict__ h1p,
    const float* __restrict__ Wa_w, const float* __restrict__ Wa_b,
    const float* __restrict__ W_hh0, const float* __restrict__ W_hh1,
    float* __restrict__ qp, float* __restrict__ hh0, float* __restrict__ hh1p)
{
    int wave = (blockIdx.x * 256 + threadIdx.x) >> 6;
    int lane = threadIdx.x & 63;
    if (wave < 16384) {                       // qp: one dot per (j,b)
        int j = wave >> 4, b = wave & 15;
        const float* w = Wa_w + (size_t)j * HSZ;
        const float* x = h1p + b * HSZ;
        float s = 0.f;
        #pragma unroll
        for (int u = 0; u < 4; ++u) {
            float4 wv = *(const float4*)(w + lane * 4 + u * 256);
            float4 xv = *(const float4*)(x + lane * 4 + u * 256);
            s += wv.x * xv.x + wv.y * xv.y + wv.z * xv.z + wv.w * xv.w;
        }
        s = wsum(s);
        if (!lane) qp[b * HSZ + j] = s + Wa_b[j];
    } else {                                   // hh0 / hh1p: 3 gate dots per (j,b)
        int idx = wave - 16384;
        const float* W; const float* x; float* out;
        if (idx < 16384) { W = W_hh0; x = h0p; out = hh0; }
        else { idx -= 16384; W = W_hh1; x = h1p; out = hh1p; }
        int j = idx >> 4, b = idx & 15;
        const float* w0 = W + (size_t)j * HSZ;
        const float* w1 = W + (size_t)(j + 2048) * HSZ;
        const float* w2 = W + (size_t)(j + 3072) * HSZ;
        const float* xb = x + b * HSZ;
        float s0 = 0.f, s1 = 0.f, s2 = 0.f;
        #pragma unroll
        for (int u = 0; u < 4; ++u) {
            float4 xv = *(const float4*)(xb + lane * 4 + u * 256);
            float4 a = *(const float4*)(w0 + lane * 4 + u * 256);
            float4 c = *(const float4*)(w1 + lane * 4 + u * 256);
            float4 d = *(const float4*)(w2 + lane * 4 + u * 256);
            s0 += a.x * xv.x + a.y * xv.y + a.z * xv.z + a.w * xv.w;
            s1 += c.x * xv.x + c.y * xv.y + c.z * xv.z + c.w * xv.w;
            s2 += d.x * xv.x + d.y * xv.y + d.z * xv.z + d.w * xv.w;
        }
        s0 = wsum(s0); s1 = wsum(s1); s2 = wsum(s2);
        if (!lane) {
            out[b * 3072 + j] = s0;
            out[b * 3072 + 1024 + j] = s1;
            out[b * 3072 + 2048 + j] = s2;
        }
    }
}

// K2: scores[b][s] = Va_b + sum_h Va[h]*tanh(qp[b][h] + kp[b][s][h])
__global__ __launch_bounds__(256) void attn_scores(
    const float* __restrict__ kp, const float* __restrict__ qp,
    const float* __restrict__ Va_w, const float* __restrict__ Va_b,
    float* __restrict__ scores)
{
    int item = (blockIdx.x * 256 + threadIdx.x) >> 6;
    int lane = threadIdx.x & 63;
    int b = item >> 8, s = item & 255;
    const float* kr = kp + (size_t)(b * SSZ + s) * HSZ;
    const float* q = qp + b * HSZ;
    float acc = 0.f;
    #pragma unroll
    for (int u = 0; u < 4; ++u) {
        float4 kv = *(const float4*)(kr + lane * 4 + u * 256);
        float4 qv = *(const float4*)(q + lane * 4 + u * 256);
        float4 vv = *(const float4*)(Va_w + lane * 4 + u * 256);
        acc += fast_tanh(kv.x + qv.x) * vv.x;
        acc += fast_tanh(kv.y + qv.y) * vv.y;
        acc += fast_tanh(kv.z + qv.z) * vv.z;
        acc += fast_tanh(kv.w + qv.w) * vv.w;
    }
    acc = wsum(acc);
    if (!lane) scores[b * SSZ + s] = acc + Va_b[0];
}

// K3: per-b softmax (redundant per chunk) + ctx chunk + attention output write
__global__ __launch_bounds__(256) void softmax_ctx(
    const float* __restrict__ scores, const float* __restrict__ enc,
    float* __restrict__ ctx, float* __restrict__ att_out, int t)
{
    int b = blockIdx.y, ch = blockIdx.x;   // ch 0..15, 64 h each
    __shared__ float att[256];
    __shared__ float red[8];
    __shared__ float part[4][64];
    int tid = threadIdx.x;
    float sc = scores[b * SSZ + tid];
    float m = sc;
    #pragma unroll
    for (int o = 32; o; o >>= 1) m = fmaxf(m, __shfl_xor(m, o, 64));
    if ((tid & 63) == 0) red[tid >> 6] = m;
    __syncthreads();
    m = fmaxf(fmaxf(red[0], red[1]), fmaxf(red[2], red[3]));
    float p = __expf(sc - m);
    float ss = p;
    #pragma unroll
    for (int o = 32; o; o >>= 1) ss += __shfl_xor(ss, o, 64);
    if ((tid & 63) == 0) red[4 + (tid >> 6)] = ss;
    __syncthreads();
    float Z = red[4] + red[5] + red[6] + red[7];
    float a = p / Z;
    att[tid] = a;
    if (ch == 0) att_out[((size_t)b * TSZ + t) * SSZ + tid] = a;
    __syncthreads();
    int h = ch * 64 + (tid & 63);
    int q = tid >> 6;
    const float* e = enc + (size_t)b * SSZ * HSZ;
    float acc = 0.f;
    for (int s = q * 64; s < q * 64 + 64; ++s)
        acc += att[s] * e[(size_t)s * HSZ + h];
    part[q][tid & 63] = acc;
    __syncthreads();
    if (tid < 64)
        ctx[b * HSZ + ch * 64 + tid] = part[0][tid] + part[1][tid] + part[2][tid] + part[3][tid];
}

// K4: h0 = lstm0(pre_emb[t] + hh0 + ctx@W_ctx^T)
__global__ __launch_bounds__(256) void lstm0(
    const float* __restrict__ ctx, const float* __restrict__ W_ih0,
    const float* __restrict__ pre_emb, const float* __restrict__ hh0,
    float* __restrict__ h0s, int t)
{
    int item = (blockIdx.x * 256 + threadIdx.x) >> 6;
    int lane = threadIdx.x & 63;
    int j = item >> 4, b = item & 15;
    const float* x = ctx + b * HSZ;
    const float* w0 = W_ih0 + (size_t)j * 2048 + 1024;
    const float* w1 = W_ih0 + (size_t)(j + 2048) * 2048 + 1024;
    const float* w2 = W_ih0 + (size_t)(j + 3072) * 2048 + 1024;
    float s0 = 0.f, s1 = 0.f, s2 = 0.f;
    #pragma unroll
    for (int u = 0; u < 4; ++u) {
        float4 xv = *(const float4*)(x + lane * 4 + u * 256);
        float4 a = *(const float4*)(w0 + lane * 4 + u * 256);
        float4 c = *(const float4*)(w1 + lane * 4 + u * 256);
        float4 d = *(const float4*)(w2 + lane * 4 + u * 256);
        s0 += a.x * xv.x + a.y * xv.y + a.z * xv.z + a.w * xv.w;
        s1 += c.x * xv.x + c.y * xv.y + c.z * xv.z + c.w * xv.w;
        s2 += d.x * xv.x + d.y * xv.y + d.z * xv.z + d.w * xv.w;
    }
    s0 = wsum(s0); s1 = wsum(s1); s2 = wsum(s2);
    if (!lane) {
        const float* pe = pre_emb + ((size_t)t * BSZ + b) * 4096;
        float gi = s0 + pe[j] + hh0[b * 3072 + j];
        float gg = s1 + pe[j + 2048] + hh0[b * 3072 + 1024 + j];
        float go = s2 + pe[j + 3072] + hh0[b * 3072 + 2048 + j];
        float c = sigmoidf(gi) * fast_tanh(gg);
        h0s[b * HSZ + j] = sigmoidf(go) * fast_tanh(c);
    }
}

// K5: h1 = lstm1(h0@W_ih1^T + b_ih1 + hh1p + b_hh1); store into state + H1[b][t]
__global__ __launch_bounds__(256) void lstm1(
    const float* __restrict__ h0s, const float* __restrict__ W_ih1,
    const float* __restrict__ b_ih1, const float* __restrict__ b_hh1,
    const float* __restrict__ hh1p, float* __restrict__ h1s,
    float* __restrict__ H1, int t)
{
    int item = (blockIdx.x * 256 + threadIdx.x) >> 6;
    int lane = threadIdx.x & 63;
    int j = item >> 4, b = item & 15;
    const float* x = h0s + b * HSZ;
    const float* w0 = W_ih1 + (size_t)j * HSZ;
    const float* w1 = W_ih1 + (size_t)(j + 2048) * HSZ;
    const float* w2 = W_ih1 + (size_t)(j + 3072) * HSZ;
    float s0 = 0.f, s1 = 0.f, s2 = 0.f;
    #pragma unroll
    for (int u = 0; u < 4; ++u) {
        float4 xv = *(const float4*)(x + lane * 4 + u * 256);
        float4 a = *(const float4*)(w0 + lane * 4 + u * 256);
        float4 c = *(const float4*)(w1 + lane * 4 + u * 256);
        float4 d = *(const float4*)(w2 + lane * 4 + u * 256);
        s0 += a.x * xv.x + a.y * xv.y + a.z * xv.z + a.w * xv.w;
        s1 += c.x * xv.x + c.y * xv.y + c.z * xv.z + c.w * xv.w;
        s2 += d.x * xv.x + d.y * xv.y + d.z * xv.z + d.w * xv.w;
    }
    s0 = wsum(s0); s1 = wsum(s1); s2 = wsum(s2);
    if (!lane) {
        float gi = s0 + hh1p[b * 3072 + j] + b_ih1[j] + b_hh1[j];
        float gg = s1 + hh1p[b * 3072 + 1024 + j] + b_ih1[j + 2048] + b_hh1[j + 2048];
        float go = s2 + hh1p[b * 3072 + 2048 + j] + b_ih1[j + 3072] + b_hh1[j + 3072];
        float c = sigmoidf(gi) * fast_tanh(gg);
        float h = sigmoidf(go) * fast_tanh(c);
        h1s[b * HSZ + j] = h;
        H1[((size_t)b * TSZ + t) * HSZ + j] = h;
    }
}

__global__ __launch_bounds__(256) void log_softmax_rows(float* __restrict__ data) {
    size_t r = blockIdx.x;
    float* row = data + r * VSZ;
    int tid = threadIdx.x;
    __shared__ float red[4];
    float m = -1e30f;
    for (int c = tid; c < VSZ; c += 256) m = fmaxf(m, row[c]);
    #pragma unroll
    for (int o = 32; o; o >>= 1) m = fmaxf(m, __shfl_xor(m, o, 64));
    if ((tid & 63) == 0) red[tid >> 6] = m;
    __syncthreads();
    m = fmaxf(fmaxf(red[0], red[1]), fmaxf(red[2], red[3]));
    float s = 0.f;
    for (int c = tid; c < VSZ; c += 256) s += __expf(row[c] - m);
    #pragma unroll
    for (int o = 32; o; o >>= 1) s += __shfl_xor(s, o, 64);
    __syncthreads();
    if ((tid & 63) == 0) red[tid >> 6] = s;
    __syncthreads();
    float lse = m + __logf(red[0] + red[1] + red[2] + red[3]);
    for (int c = tid; c < VSZ; c += 256) row[c] -= lse;
}

__global__ __launch_bounds__(256) void copy_hfinal(const float* __restrict__ h0s,
                                                   const float* __restrict__ h1s,
                                                   float* __restrict__ out_h) {
    int i = blockIdx.x * 256 + threadIdx.x;
    if (i < 16384) out_h[i] = h0s[i];
    else if (i < 32768) out_h[i] = h1s[i - 16384];
}

extern "C" void kernel_launch(void* const* d_in, const int* in_sizes, int n_in,
                              void* d_out, int out_size, void* d_ws, size_t ws_size,
                              hipStream_t stream)
{
    const float* enc   = (const float*)d_in[0];
    const float* ehid  = (const float*)d_in[1];
    const int*   targ  = (const int*)d_in[2];
    const float* emb   = (const float*)d_in[3];
    const float* Wa_w  = (const float*)d_in[4];
    const float* Wa_b  = (const float*)d_in[5];
    const float* Ua_w  = (const float*)d_in[6];
    const float* Ua_b  = (const float*)d_in[7];
    const float* Va_w  = (const float*)d_in[8];
    const float* Va_b  = (const float*)d_in[9];
    const float* W_ih0 = (const float*)d_in[10];
    const float* W_hh0 = (const float*)d_in[11];
    const float* b_ih0 = (const float*)d_in[12];
    const float* b_hh0 = (const float*)d_in[13];
    const float* W_ih1 = (const float*)d_in[14];
    const float* W_hh1 = (const float*)d_in[15];
    const float* b_ih1 = (const float*)d_in[16];
    const float* b_hh1 = (const float*)d_in[17];
    const float* out_w = (const float*)d_in[18];
    const float* out_b = (const float*)d_in[19];

    float* ws = (float*)d_ws;
    float* kp      = ws;                    // 4,194,304   keys_proj (B,S,H)
    float* pre_emb = kp + 4194304;          // 13,107,200  (T,B,4H) emb@W_ih0_emb^T + biases
    float* H1      = pre_emb + 13107200;    // 3,276,800   h1 history, [b][t][H]
    float* qp      = H1 + 3276800;          // 16384
    float* hh0     = qp + 16384;            // 49152 (i,g,o)
    float* hh1p    = hh0 + 49152;           // 49152
    float* scores  = hh1p + 49152;          // 4096
    float* ctx     = scores + 4096;         // 16384
    float* h0s     = ctx + 16384;           // 16384
    float* h1s     = h0s + 16384;           // 16384
    int*   tok     = (int*)(h1s + 16384);   // 3200

    float* out_lp  = (float*)d_out;                 // (B,T,V)
    float* out_h   = out_lp + (size_t)BSZ * TSZ * VSZ; // (L,B,H)
    float* out_att = out_h + 2 * BSZ * HSZ;         // (B,T,S)

    build_tokens<<<13, 256, 0, stream>>>(targ, tok);
    // keys_proj = enc @ Ua_w^T + Ua_b : M=4096, N=1024, K=1024
    gemm_nt<<<dim3(16, 64), 256, 0, stream>>>(enc, nullptr, Ua_w, 1024, Ua_b, nullptr,
                                              kp, 4096, 1024, 1024);
    // pre_emb = embedding[tok] @ W_ih0[:, :1024]^T + b_ih0 + b_hh0 : M=3200, N=4096
    gemm_nt<<<dim3(64, 50), 256, 0, stream>>>(emb, tok, W_ih0, 2048, b_ih0, b_hh0,
                                              pre_emb, 3200, 4096, 1024);

    for (int t = 0; t < TSZ; ++t) {
        const float* h0p = t ? h0s : ehid;
        const float* h1p = t ? h1s : ehid + BSZ * HSZ;
        step_pre<<<12288, 256, 0, stream>>>(h0p, h1p, Wa_w, Wa_b, W_hh0, W_hh1,
                                            qp, hh0, hh1p);
        attn_scores<<<1024, 256, 0, stream>>>(kp, qp, Va_w, Va_b, scores);
        softmax_ctx<<<dim3(16, 16), 256, 0, stream>>>(scores, enc, ctx, out_att, t);
        lstm0<<<4096, 256, 0, stream>>>(ctx, W_ih0, pre_emb, hh0, h0s, t);
        lstm1<<<4096, 256, 0, stream>>>(h0s, W_ih1, b_ih1, b_hh1, hh1p, h1s, H1, t);
    }

    // logits = H1 @ out_w^T + out_b, written straight into d_out rows (b*T+t)
    gemm_nt<<<dim3(500, 50), 256, 0, stream>>>(H1, nullptr, out_w, 1024, out_b, nullptr,
                                               out_lp, 3200, 32000, 1024);
    log_softmax_rows<<<3200, 256, 0, stream>>>(out_lp);
    copy_hfinal<<<128, 256, 0, stream>>>(h0s, h1s, out_h);
}